// Round 1
// baseline (1522.677 us; speedup 1.0000x reference)
//
#include <hip/hip_runtime.h>

#define D 128
#define NH 8
#define FOUT 16
#define NEG_SLOPE 0.2f

// ---- Kernel 0: combined trg weight: wc[h][d] = sum_f a_trg[h,f] * W_trg[h*16+f, d]
__global__ void wcomb_kernel(const float* __restrict__ W_trg,
                             const float* __restrict__ a_trg,
                             float* __restrict__ wc) {
    int t = blockIdx.x * blockDim.x + threadIdx.x;
    if (t >= NH * D) return;
    int h = t >> 7, d = t & 127;
    float acc = 0.f;
#pragma unroll
    for (int f = 0; f < FOUT; ++f)
        acc += a_trg[h * FOUT + f] * W_trg[(h * FOUT + f) * D + d];
    wc[h * D + d] = acc;
}

// ---- Kernel 1: per node: src_proj (128), s_src (8), s_trg (8)
__global__ void proj_kernel(const float* __restrict__ src,
                            const float* __restrict__ trg,
                            const float* __restrict__ W_src,
                            const float* __restrict__ a_src,
                            const float* __restrict__ wc,
                            float* __restrict__ src_proj,
                            float* __restrict__ s_src,
                            float* __restrict__ s_trg) {
    int n = blockIdx.x;
    int t = threadIdx.x;  // 128 threads
    __shared__ float srow[D];
    __shared__ float trow[D];
    srow[t] = src[n * D + t];
    trow[t] = trg[n * D + t];
    __syncthreads();

    // output feature o = t : dot(src row, W_src row o)
    float acc = 0.f;
    const float* w = W_src + t * D;
#pragma unroll 8
    for (int d = 0; d < D; ++d) acc += srow[d] * w[d];
    src_proj[n * D + t] = acc;

    // s_src[n, t>>4] = sum over group of 16 of acc * a_src[t]
    float v = acc * a_src[t];
#pragma unroll
    for (int off = 8; off; off >>= 1) v += __shfl_xor(v, off, 16);
    if ((t & 15) == 0) s_src[n * NH + (t >> 4)] = v;

    // s_trg[n, h] = dot(trg row, wc[h])
    int h = t >> 4, l = t & 15;
    float u = 0.f;
#pragma unroll
    for (int d = l; d < D; d += 16) u += trow[d] * wc[h * D + d];
#pragma unroll
    for (int off = 8; off; off >>= 1) u += __shfl_xor(u, off, 16);
    if (l == 0) s_trg[n * NH + h] = u;
}

// ---- Kernel 2a: per-block max of leaky-relu scores
__global__ void max1_kernel(const int* __restrict__ ei,
                            const float* __restrict__ s_src,
                            const float* __restrict__ s_trg,
                            float* __restrict__ bmax, int E) {
    float m = -1e30f;
    for (int e = blockIdx.x * blockDim.x + threadIdx.x; e < E;
         e += gridDim.x * blockDim.x) {
        int si = ei[e], ti = ei[E + e];
        const float* ps = s_src + si * NH;
        const float* pt = s_trg + ti * NH;
#pragma unroll
        for (int h = 0; h < NH; ++h) {
            float sc = ps[h] + pt[h];
            sc = sc > 0.f ? sc : NEG_SLOPE * sc;
            m = fmaxf(m, sc);
        }
    }
    __shared__ float red[256];
    red[threadIdx.x] = m;
    __syncthreads();
    for (int s = 128; s; s >>= 1) {
        if (threadIdx.x < s)
            red[threadIdx.x] = fmaxf(red[threadIdx.x], red[threadIdx.x + s]);
        __syncthreads();
    }
    if (threadIdx.x == 0) bmax[blockIdx.x] = red[0];
}

// ---- Kernel 2b: reduce block maxima to scalar
__global__ void max2_kernel(const float* __restrict__ bmax,
                            float* __restrict__ gmax, int n) {
    __shared__ float red[1024];
    float m = -1e30f;
    for (int i = threadIdx.x; i < n; i += blockDim.x) m = fmaxf(m, bmax[i]);
    red[threadIdx.x] = m;
    __syncthreads();
    for (int s = 512; s; s >>= 1) {
        if (threadIdx.x < s)
            red[threadIdx.x] = fmaxf(red[threadIdx.x], red[threadIdx.x + s]);
        __syncthreads();
    }
    if (threadIdx.x == 0) gmax[0] = red[0];
}

// ---- Kernel 3: denom[t,h] += exp(score - gmax)
__global__ void denom_kernel(const int* __restrict__ ei,
                             const float* __restrict__ s_src,
                             const float* __restrict__ s_trg,
                             const float* __restrict__ gmax,
                             float* __restrict__ denom, int E) {
    float gm = gmax[0];
    int total = E * NH;
    for (int w = blockIdx.x * blockDim.x + threadIdx.x; w < total;
         w += gridDim.x * blockDim.x) {
        int e = w >> 3, h = w & 7;
        int si = ei[e], ti = ei[E + e];
        float sc = s_src[si * NH + h] + s_trg[ti * NH + h];
        sc = sc > 0.f ? sc : NEG_SLOPE * sc;
        atomicAdd(denom + ti * NH + h, expf(sc - gm));
    }
}

// ---- Kernel 4: out[t,f] += src_proj[s,f] * attn(e, f>>4)
__global__ void out_kernel(const int* __restrict__ ei,
                           const float* __restrict__ s_src,
                           const float* __restrict__ s_trg,
                           const float* __restrict__ denom,
                           const float* __restrict__ gmax,
                           const float* __restrict__ src_proj,
                           float* __restrict__ out, int E) {
    float gm = gmax[0];
    long total = (long)E * D;
    for (long w = blockIdx.x * (long)blockDim.x + threadIdx.x; w < total;
         w += (long)gridDim.x * blockDim.x) {
        int e = (int)(w >> 7);
        int f = (int)(w & 127);
        int h = f >> 4;
        int si = ei[e], ti = ei[E + e];
        float sc = s_src[si * NH + h] + s_trg[ti * NH + h];
        sc = sc > 0.f ? sc : NEG_SLOPE * sc;
        float attn = expf(sc - gm) / (denom[ti * NH + h] + 1e-16f);
        atomicAdd(out + ti * D + f, src_proj[si * D + f] * attn);
    }
}

extern "C" void kernel_launch(void* const* d_in, const int* in_sizes, int n_in,
                              void* d_out, int out_size, void* d_ws, size_t ws_size,
                              hipStream_t stream) {
    const float* trg   = (const float*)d_in[0];
    const float* src   = (const float*)d_in[1];
    const int*   ei    = (const int*)d_in[2];
    const float* W_trg = (const float*)d_in[3];
    const float* W_src = (const float*)d_in[4];
    const float* a_src = (const float*)d_in[5];
    const float* a_trg = (const float*)d_in[6];
    float* out = (float*)d_out;

    const int N = in_sizes[0] / D;   // 100000
    const int E = in_sizes[2] / 2;   // 1600000

    // workspace layout (floats)
    float* ws     = (float*)d_ws;
    float* wc     = ws;                      // 8*128
    float* s_src  = wc + NH * D;             // N*8
    float* s_trg  = s_src + (size_t)N * NH;  // N*8
    float* denom  = s_trg + (size_t)N * NH;  // N*8
    float* bmax   = denom + (size_t)N * NH;  // 1024
    float* gmax   = bmax + 1024;             // 1 (pad to 4)
    float* proj   = gmax + 4;                // N*128

    hipMemsetAsync(out, 0, (size_t)out_size * sizeof(float), stream);
    hipMemsetAsync(denom, 0, (size_t)N * NH * sizeof(float), stream);

    wcomb_kernel<<<1, 1024, 0, stream>>>(W_trg, a_trg, wc);
    proj_kernel<<<N, D, 0, stream>>>(src, trg, W_src, a_src, wc, proj, s_src, s_trg);
    max1_kernel<<<1024, 256, 0, stream>>>(ei, s_src, s_trg, bmax, E);
    max2_kernel<<<1, 1024, 0, stream>>>(bmax, gmax, 1024);
    denom_kernel<<<2048, 256, 0, stream>>>(ei, s_src, s_trg, gmax, denom, E);
    out_kernel<<<4096, 256, 0, stream>>>(ei, s_src, s_trg, denom, gmax, proj, out, E);
}

// Round 2
// 495.250 us; speedup vs baseline: 3.0746x; 3.0746x over previous
//
#include <hip/hip_runtime.h>

#define D 128
#define NH 8
#define FOUT 16
#define NEG_SLOPE 0.2f
#define TNODES 32
#define SCAN_BS 1024

__device__ __forceinline__ unsigned enc_f(float f) {
    unsigned u = __float_as_uint(f);
    return (u & 0x80000000u) ? ~u : (u | 0x80000000u);
}
__device__ __forceinline__ float dec_f(unsigned u) {
    u = (u & 0x80000000u) ? (u & 0x7fffffffu) : ~u;
    return __uint_as_float(u);
}

// ---- prep: WT[d][o] = W_src[o][d];  wc[h][d] = sum_f a_trg[h,f]*W_trg[h*16+f][d]
__global__ void prep_kernel(const float* __restrict__ W_src,
                            const float* __restrict__ W_trg,
                            const float* __restrict__ a_trg,
                            float* __restrict__ WT, float* __restrict__ wc) {
    int t = blockIdx.x * blockDim.x + threadIdx.x;
    if (t < D * D) {
        int o = t >> 7, d = t & 127;
        WT[d * D + o] = W_src[t];
    } else if (t < D * D + NH * D) {
        int u = t - D * D;
        int h = u >> 7, d = u & 127;
        float acc = 0.f;
#pragma unroll
        for (int f = 0; f < FOUT; ++f)
            acc += a_trg[h * FOUT + f] * W_trg[(h * FOUT + f) * D + d];
        wc[h * D + d] = acc;
    }
}

// ---- projection: proj (N x 128), s_src (N x 8), s_trg (N x 8), per-array global max
__global__ __launch_bounds__(256) void proj_kernel(
    const float* __restrict__ src, const float* __restrict__ trg,
    const float* __restrict__ WT, const float* __restrict__ a_src,
    const float* __restrict__ wc,
    float* __restrict__ proj, float* __restrict__ s_src, float* __restrict__ s_trg,
    unsigned* __restrict__ gmax_enc, int N) {
    int n0 = blockIdx.x * TNODES;
    int tid = threadIdx.x;
    __shared__ float st[TNODES][D];       // src tile
    __shared__ float tt[TNODES][D + 4];   // trg tile, padded rows (132 words)
    __shared__ float red[256];

    // stage src tile (32*128 floats) via float4, fully coalesced
    {
        const float4* src4 = (const float4*)(src + (size_t)n0 * D);
        const float4* trg4 = (const float4*)(trg + (size_t)n0 * D);
        for (int i = tid; i < TNODES * 32; i += 256) {
            ((float4*)st)[i] = src4[i];
            int n = i >> 5, c = i & 31;
            *((float4*)&tt[n][c * 4]) = trg4[i];
        }
    }
    __syncthreads();

    int q = tid & 31;    // feature quad: features 4q..4q+3
    int slot = tid >> 5; // 0..7, nodes slot*4..slot*4+3
    float acc[4][4] = {{0.f}};

    for (int d = 0; d < D; d += 4) {
        float4 w[4];
#pragma unroll
        for (int k = 0; k < 4; ++k)
            w[k] = *((const float4*)(WT + (d + k) * D + 4 * q));
#pragma unroll
        for (int r = 0; r < 4; ++r) {
            float4 sv = *((const float4*)&st[slot * 4 + r][d]);
            float sa[4] = {sv.x, sv.y, sv.z, sv.w};
#pragma unroll
            for (int k = 0; k < 4; ++k) {
                acc[r][0] += sa[k] * w[k].x;
                acc[r][1] += sa[k] * w[k].y;
                acc[r][2] += sa[k] * w[k].z;
                acc[r][3] += sa[k] * w[k].w;
            }
        }
    }

    // write proj + s_src (fold a_src), track max
    float lmax = -1e30f;
    float4 av = ((const float4*)a_src)[q];
#pragma unroll
    for (int r = 0; r < 4; ++r) {
        int n = slot * 4 + r;
        *((float4*)(proj + ((size_t)(n0 + n)) * D + 4 * q)) =
            make_float4(acc[r][0], acc[r][1], acc[r][2], acc[r][3]);
        float p = acc[r][0] * av.x + acc[r][1] * av.y + acc[r][2] * av.z + acc[r][3] * av.w;
        p += __shfl_xor(p, 1);
        p += __shfl_xor(p, 2);
        // all 4 lanes of the quad-group hold the head sum now
        if ((q & 3) == 0) s_src[(size_t)(n0 + n) * NH + (q >> 2)] = p;
        lmax = fmaxf(lmax, p);
    }

    // s_trg: thread -> (node = tid>>3, head = tid&7)
    int n2 = tid >> 3, h2 = tid & 7;
    float dot = 0.f;
    for (int c = 0; c < 32; ++c) {
        float4 tv = *((const float4*)&tt[n2][c * 4]);
        float4 wv = ((const float4*)(wc + h2 * D))[c];
        dot += tv.x * wv.x + tv.y * wv.y + tv.z * wv.z + tv.w * wv.w;
    }
    s_trg[(size_t)(n0 + n2) * NH + h2] = dot;

    // block max of s_src candidates -> gmax_enc[0]
    red[tid] = lmax;
    __syncthreads();
    for (int s = 128; s; s >>= 1) {
        if (tid < s) red[tid] = fmaxf(red[tid], red[tid + s]);
        __syncthreads();
    }
    if (tid == 0) atomicMax(gmax_enc + 0, enc_f(red[0]));
    __syncthreads();
    // block max of s_trg -> gmax_enc[1]
    red[tid] = dot;
    __syncthreads();
    for (int s = 128; s; s >>= 1) {
        if (tid < s) red[tid] = fmaxf(red[tid], red[tid + s]);
        __syncthreads();
    }
    if (tid == 0) atomicMax(gmax_enc + 1, enc_f(red[0]));
}

// ---- combine maxes: M = max(s_src) + max(s_trg)  (>= true max; cancels in softmax)
__global__ void finishmax_kernel(const unsigned* __restrict__ ge, float* __restrict__ gmaxf) {
    gmaxf[0] = dec_f(ge[0]) + dec_f(ge[1]);
}

// ---- histogram of targets
__global__ void hist_kernel(const int* __restrict__ ei, int* __restrict__ counts, int E) {
    int e = blockIdx.x * blockDim.x + threadIdx.x;
    if (e < E) atomicAdd(counts + ei[E + e], 1);
}

// ---- scan over counts -> cursor (exclusive offsets), block-wise
__global__ void scan1_kernel(const int* __restrict__ counts, int* __restrict__ cursor,
                             int* __restrict__ bsum, int N) {
    __shared__ int tmp[SCAN_BS];
    int t = threadIdx.x, g = blockIdx.x * SCAN_BS + t;
    int v = (g < N) ? counts[g] : 0;
    tmp[t] = v;
    __syncthreads();
    for (int off = 1; off < SCAN_BS; off <<= 1) {
        int x = (t >= off) ? tmp[t - off] : 0;
        __syncthreads();
        tmp[t] += x;
        __syncthreads();
    }
    if (g < N) cursor[g] = tmp[t] - v;  // exclusive within block
    if (t == SCAN_BS - 1) bsum[blockIdx.x] = tmp[t];
}
__global__ void scan2_kernel(int* __restrict__ bsum, int nb) {
    __shared__ int tmp[128];
    int t = threadIdx.x;
    int v = (t < nb) ? bsum[t] : 0;
    tmp[t] = v;
    __syncthreads();
    for (int off = 1; off < 128; off <<= 1) {
        int x = (t >= off) ? tmp[t - off] : 0;
        __syncthreads();
        tmp[t] += x;
        __syncthreads();
    }
    if (t < nb) bsum[t] = tmp[t] - v;  // exclusive block offsets
}
__global__ void scan3_kernel(int* __restrict__ cursor, const int* __restrict__ bsum, int N) {
    int g = blockIdx.x * SCAN_BS + threadIdx.x;
    if (g < N) cursor[g] += bsum[blockIdx.x];
}

// ---- scatter edges into CSR buckets (cursor: start -> end as it fills)
__global__ void scatter_kernel(const int* __restrict__ ei, int* __restrict__ cursor,
                               int* __restrict__ perm_src, int E) {
    int e = blockIdx.x * blockDim.x + threadIdx.x;
    if (e < E) {
        int si = ei[e], ti = ei[E + e];
        int pos = atomicAdd(cursor + ti, 1);
        perm_src[pos] = si;
    }
}

// ---- per-target aggregation: atomic-free, fused softmax normalize
__global__ __launch_bounds__(128) void agg_kernel(
    const int* __restrict__ cursor_end, const int* __restrict__ counts,
    const int* __restrict__ perm_src,
    const float* __restrict__ s_src, const float* __restrict__ s_trg,
    const float* __restrict__ proj, const float* __restrict__ gmaxf,
    float* __restrict__ out) {
    int n = blockIdx.x;
    int f = threadIdx.x;     // 0..127
    int h = f >> 4;
    int cnt = counts[n];
    int start = cursor_end[n] - cnt;
    float M = gmaxf[0];
    float stg = s_trg[(size_t)n * NH + h];
    float acc = 0.f, wsum = 0.f;
    __shared__ int sie[128];

    for (int base = 0; base < cnt; base += 128) {
        int pv = (base + f < cnt) ? perm_src[start + base + f] : 0;
        __syncthreads();
        sie[f] = pv;
        __syncthreads();
        int m = min(128, cnt - base);
#pragma unroll 2
        for (int j = 0; j < m; ++j) {
            int si = sie[j];
            float sc = s_src[(size_t)si * NH + h] + stg;
            sc = sc > 0.f ? sc : NEG_SLOPE * sc;
            float w = expf(sc - M);
            wsum += w;
            acc += w * proj[(size_t)si * D + f];
        }
    }
    out[(size_t)n * D + f] = acc / (wsum + 1e-16f);
}

extern "C" void kernel_launch(void* const* d_in, const int* in_sizes, int n_in,
                              void* d_out, int out_size, void* d_ws, size_t ws_size,
                              hipStream_t stream) {
    const float* trg   = (const float*)d_in[0];
    const float* src   = (const float*)d_in[1];
    const int*   ei    = (const int*)d_in[2];
    const float* W_trg = (const float*)d_in[3];
    const float* W_src = (const float*)d_in[4];
    const float* a_src = (const float*)d_in[5];
    const float* a_trg = (const float*)d_in[6];
    float* out = (float*)d_out;

    const int N = in_sizes[0] / D;   // 100000
    const int E = in_sizes[2] / 2;   // 1600000

    // workspace layout (4-byte elems)
    float* ws       = (float*)d_ws;
    float* WT       = ws;                          // 128*128
    float* wc       = WT + D * D;                  // 8*128
    unsigned* gmaxe = (unsigned*)(wc + NH * D);    // 2 (pad 4)
    float* gmaxf    = (float*)(gmaxe + 4);         // 1 (pad 4)
    float* s_src    = gmaxf + 4;                   // N*8
    float* s_trg    = s_src + (size_t)N * NH;      // N*8
    int*   counts   = (int*)(s_trg + (size_t)N * NH);  // N
    int*   cursor   = counts + N;                  // N
    int*   bsum     = cursor + N;                  // 128
    int*   perm_src = bsum + 128;                  // E
    float* proj     = (float*)(perm_src + E);      // N*128

    const int NB = (N + SCAN_BS - 1) / SCAN_BS;    // 98

    hipMemsetAsync(counts, 0, (size_t)N * sizeof(int), stream);
    hipMemsetAsync(gmaxe, 0, 4 * sizeof(unsigned), stream);

    prep_kernel<<<(D * D + NH * D + 255) / 256, 256, 0, stream>>>(W_src, W_trg, a_trg, WT, wc);
    proj_kernel<<<N / TNODES, 256, 0, stream>>>(src, trg, WT, a_src, wc,
                                                proj, s_src, s_trg, gmaxe, N);
    finishmax_kernel<<<1, 1, 0, stream>>>(gmaxe, gmaxf);
    hist_kernel<<<(E + 255) / 256, 256, 0, stream>>>(ei, counts, E);
    scan1_kernel<<<NB, SCAN_BS, 0, stream>>>(counts, cursor, bsum, N);
    scan2_kernel<<<1, 128, 0, stream>>>(bsum, NB);
    scan3_kernel<<<NB, SCAN_BS, 0, stream>>>(cursor, bsum, N);
    scatter_kernel<<<(E + 255) / 256, 256, 0, stream>>>(ei, cursor, perm_src, E);
    agg_kernel<<<N, 128, 0, stream>>>(cursor, counts, perm_src,
                                      s_src, s_trg, proj, gmaxf, out);
}

// Round 3
// 488.105 us; speedup vs baseline: 3.1196x; 1.0146x over previous
//
#include <hip/hip_runtime.h>

#define D 128
#define NH 8
#define FOUT 16
#define NEG_SLOPE 0.2f
#define TNODES 32
#define SCAN_BS 1024

__device__ __forceinline__ unsigned enc_f(float f) {
    unsigned u = __float_as_uint(f);
    return (u & 0x80000000u) ? ~u : (u | 0x80000000u);
}
__device__ __forceinline__ float dec_f(unsigned u) {
    u = (u & 0x80000000u) ? (u & 0x7fffffffu) : ~u;
    return __uint_as_float(u);
}

// ---- prep: WT[d][o] = W_src[o][d];  wc[h][d] = sum_f a_trg[h,f]*W_trg[h*16+f][d]
__global__ void prep_kernel(const float* __restrict__ W_src,
                            const float* __restrict__ W_trg,
                            const float* __restrict__ a_trg,
                            float* __restrict__ WT, float* __restrict__ wc) {
    int t = blockIdx.x * blockDim.x + threadIdx.x;
    if (t < D * D) {
        int o = t >> 7, d = t & 127;
        WT[d * D + o] = W_src[t];
    } else if (t < D * D + NH * D) {
        int u = t - D * D;
        int h = u >> 7, d = u & 127;
        float acc = 0.f;
#pragma unroll
        for (int f = 0; f < FOUT; ++f)
            acc += a_trg[h * FOUT + f] * W_trg[(h * FOUT + f) * D + d];
        wc[h * D + d] = acc;
    }
}

// ---- projection: proj (N x 128), s_src (N x 8), s_trg (N x 8), per-array global max
__global__ __launch_bounds__(256) void proj_kernel(
    const float* __restrict__ src, const float* __restrict__ trg,
    const float* __restrict__ WT, const float* __restrict__ a_src,
    const float* __restrict__ wc,
    float* __restrict__ proj, float* __restrict__ s_src, float* __restrict__ s_trg,
    unsigned* __restrict__ gmax_enc, int N) {
    int n0 = blockIdx.x * TNODES;
    int tid = threadIdx.x;
    __shared__ float st[TNODES][D];       // src tile
    __shared__ float tt[TNODES][D + 4];   // trg tile, padded rows
    __shared__ float red[256];

    {
        const float4* src4 = (const float4*)(src + (size_t)n0 * D);
        const float4* trg4 = (const float4*)(trg + (size_t)n0 * D);
        for (int i = tid; i < TNODES * 32; i += 256) {
            ((float4*)st)[i] = src4[i];
            int n = i >> 5, c = i & 31;
            *((float4*)&tt[n][c * 4]) = trg4[i];
        }
    }
    __syncthreads();

    int q = tid & 31;    // feature quad: features 4q..4q+3
    int slot = tid >> 5; // 0..7, nodes slot*4..slot*4+3
    float acc[4][4] = {{0.f}};

    for (int d = 0; d < D; d += 4) {
        float4 w[4];
#pragma unroll
        for (int k = 0; k < 4; ++k)
            w[k] = *((const float4*)(WT + (d + k) * D + 4 * q));
#pragma unroll
        for (int r = 0; r < 4; ++r) {
            float4 sv = *((const float4*)&st[slot * 4 + r][d]);
            float sa[4] = {sv.x, sv.y, sv.z, sv.w};
#pragma unroll
            for (int k = 0; k < 4; ++k) {
                acc[r][0] += sa[k] * w[k].x;
                acc[r][1] += sa[k] * w[k].y;
                acc[r][2] += sa[k] * w[k].z;
                acc[r][3] += sa[k] * w[k].w;
            }
        }
    }

    float lmax = -1e30f;
    float4 av = ((const float4*)a_src)[q];
#pragma unroll
    for (int r = 0; r < 4; ++r) {
        int n = slot * 4 + r;
        *((float4*)(proj + ((size_t)(n0 + n)) * D + 4 * q)) =
            make_float4(acc[r][0], acc[r][1], acc[r][2], acc[r][3]);
        float p = acc[r][0] * av.x + acc[r][1] * av.y + acc[r][2] * av.z + acc[r][3] * av.w;
        p += __shfl_xor(p, 1);
        p += __shfl_xor(p, 2);
        if ((q & 3) == 0) s_src[(size_t)(n0 + n) * NH + (q >> 2)] = p;
        lmax = fmaxf(lmax, p);
    }

    int n2 = tid >> 3, h2 = tid & 7;
    float dot = 0.f;
    for (int c = 0; c < 32; ++c) {
        float4 tv = *((const float4*)&tt[n2][c * 4]);
        float4 wv = ((const float4*)(wc + h2 * D))[c];
        dot += tv.x * wv.x + tv.y * wv.y + tv.z * wv.z + tv.w * wv.w;
    }
    s_trg[(size_t)(n0 + n2) * NH + h2] = dot;

    red[tid] = lmax;
    __syncthreads();
    for (int s = 128; s; s >>= 1) {
        if (tid < s) red[tid] = fmaxf(red[tid], red[tid + s]);
        __syncthreads();
    }
    if (tid == 0) atomicMax(gmax_enc + 0, enc_f(red[0]));
    __syncthreads();
    red[tid] = dot;
    __syncthreads();
    for (int s = 128; s; s >>= 1) {
        if (tid < s) red[tid] = fmaxf(red[tid], red[tid + s]);
        __syncthreads();
    }
    if (tid == 0) atomicMax(gmax_enc + 1, enc_f(red[0]));
}

// ---- combine maxes: M = max(s_src) + max(s_trg)  (>= true max; cancels in softmax)
__global__ void finishmax_kernel(const unsigned* __restrict__ ge, float* __restrict__ gmaxf) {
    gmaxf[0] = dec_f(ge[0]) + dec_f(ge[1]);
}

// ---- histogram of targets
__global__ void hist_kernel(const int* __restrict__ ei, int* __restrict__ counts, int E) {
    int e = blockIdx.x * blockDim.x + threadIdx.x;
    if (e < E) atomicAdd(counts + ei[E + e], 1);
}

// ---- scan over counts -> cursor (exclusive offsets), block-wise
__global__ void scan1_kernel(const int* __restrict__ counts, int* __restrict__ cursor,
                             int* __restrict__ bsum, int N) {
    __shared__ int tmp[SCAN_BS];
    int t = threadIdx.x, g = blockIdx.x * SCAN_BS + t;
    int v = (g < N) ? counts[g] : 0;
    tmp[t] = v;
    __syncthreads();
    for (int off = 1; off < SCAN_BS; off <<= 1) {
        int x = (t >= off) ? tmp[t - off] : 0;
        __syncthreads();
        tmp[t] += x;
        __syncthreads();
    }
    if (g < N) cursor[g] = tmp[t] - v;
    if (t == SCAN_BS - 1) bsum[blockIdx.x] = tmp[t];
}
__global__ void scan2_kernel(int* __restrict__ bsum, int nb) {
    __shared__ int tmp[128];
    int t = threadIdx.x;
    int v = (t < nb) ? bsum[t] : 0;
    tmp[t] = v;
    __syncthreads();
    for (int off = 1; off < 128; off <<= 1) {
        int x = (t >= off) ? tmp[t - off] : 0;
        __syncthreads();
        tmp[t] += x;
        __syncthreads();
    }
    if (t < nb) bsum[t] = tmp[t] - v;
}
__global__ void scan3_kernel(int* __restrict__ cursor, const int* __restrict__ bsum, int N) {
    int g = blockIdx.x * SCAN_BS + threadIdx.x;
    if (g < N) cursor[g] += bsum[blockIdx.x];
}

// ---- scatter edges into CSR buckets
__global__ void scatter_kernel(const int* __restrict__ ei, int* __restrict__ cursor,
                               int* __restrict__ perm_src, int E) {
    int e = blockIdx.x * blockDim.x + threadIdx.x;
    if (e < E) {
        int si = ei[e], ti = ei[E + e];
        int pos = atomicAdd(cursor + ti, 1);
        perm_src[pos] = si;
    }
}

// ---- per-target aggregation: atomic-free; per-edge head weights computed once in LDS
__global__ __launch_bounds__(128) void agg_kernel(
    const int* __restrict__ cursor_end, const int* __restrict__ counts,
    const int* __restrict__ perm_src,
    const float* __restrict__ s_src, const float* __restrict__ s_trg,
    const float* __restrict__ proj, const float* __restrict__ gmaxf,
    float* __restrict__ out) {
    int n = blockIdx.x;
    int f = threadIdx.x;     // 0..127
    int h = f >> 4;
    int cnt = counts[n];
    int start = cursor_end[n] - cnt;
    float M = gmaxf[0];
    __shared__ float stg_sh[NH];
    __shared__ int sie[128];
    __shared__ float wls[128][NH + 1];   // padded: write addr 9f+h -> 2-way max (free)
    if (f < NH) stg_sh[f] = s_trg[(size_t)n * NH + f];

    float acc = 0.f, wsum = 0.f;
    for (int base = 0; base < cnt; base += 128) {
        int idx = base + f;
        __syncthreads();   // guards stg_sh (1st iter) + prev-iter LDS reads
        if (idx < cnt) {
            int si = perm_src[start + idx];
            sie[f] = si;
            const float* ps = s_src + (size_t)si * NH;
#pragma unroll
            for (int hh = 0; hh < NH; ++hh) {
                float sc = ps[hh] + stg_sh[hh];
                sc = sc > 0.f ? sc : NEG_SLOPE * sc;
                wls[f][hh] = __expf(sc - M);
            }
        }
        __syncthreads();
        int m = min(128, cnt - base);
#pragma unroll 4
        for (int j = 0; j < m; ++j) {
            int si = sie[j];
            float w = wls[j][h];
            wsum += w;
            acc += w * proj[(size_t)si * D + f];
        }
    }
    out[(size_t)n * D + f] = acc / (wsum + 1e-16f);
}

extern "C" void kernel_launch(void* const* d_in, const int* in_sizes, int n_in,
                              void* d_out, int out_size, void* d_ws, size_t ws_size,
                              hipStream_t stream) {
    const float* trg   = (const float*)d_in[0];
    const float* src   = (const float*)d_in[1];
    const int*   ei    = (const int*)d_in[2];
    const float* W_trg = (const float*)d_in[3];
    const float* W_src = (const float*)d_in[4];
    const float* a_src = (const float*)d_in[5];
    const float* a_trg = (const float*)d_in[6];
    float* out = (float*)d_out;

    const int N = in_sizes[0] / D;   // 100000
    const int E = in_sizes[2] / 2;   // 1600000

    float* ws       = (float*)d_ws;
    float* WT       = ws;                          // 128*128
    float* wc       = WT + D * D;                  // 8*128
    unsigned* gmaxe = (unsigned*)(wc + NH * D);    // 2 (pad 4)
    float* gmaxf    = (float*)(gmaxe + 4);         // 1 (pad 4)
    float* s_src    = gmaxf + 4;                   // N*8
    float* s_trg    = s_src + (size_t)N * NH;      // N*8
    int*   counts   = (int*)(s_trg + (size_t)N * NH);  // N
    int*   cursor   = counts + N;                  // N
    int*   bsum     = cursor + N;                  // 128
    int*   perm_src = bsum + 128;                  // E
    float* proj     = (float*)(perm_src + E);      // N*128

    const int NB = (N + SCAN_BS - 1) / SCAN_BS;    // 98

    hipMemsetAsync(counts, 0, (size_t)N * sizeof(int), stream);
    hipMemsetAsync(gmaxe, 0, 4 * sizeof(unsigned), stream);

    prep_kernel<<<(D * D + NH * D + 255) / 256, 256, 0, stream>>>(W_src, W_trg, a_trg, WT, wc);
    proj_kernel<<<N / TNODES, 256, 0, stream>>>(src, trg, WT, a_src, wc,
                                                proj, s_src, s_trg, gmaxe, N);
    finishmax_kernel<<<1, 1, 0, stream>>>(gmaxe, gmaxf);
    hist_kernel<<<(E + 255) / 256, 256, 0, stream>>>(ei, counts, E);
    scan1_kernel<<<NB, SCAN_BS, 0, stream>>>(counts, cursor, bsum, N);
    scan2_kernel<<<1, 128, 0, stream>>>(bsum, NB);
    scan3_kernel<<<NB, SCAN_BS, 0, stream>>>(cursor, bsum, N);
    scatter_kernel<<<(E + 255) / 256, 256, 0, stream>>>(ei, cursor, perm_src, E);
    agg_kernel<<<N, 128, 0, stream>>>(cursor, counts, perm_src,
                                      s_src, s_trg, proj, gmaxf, out);
}

// Round 4
// 417.508 us; speedup vs baseline: 3.6471x; 1.1691x over previous
//
#include <hip/hip_runtime.h>

#define D 128
#define NH 8
#define FOUT 16
#define NEG_SLOPE 0.2f
#define TNODES 32
#define SCAN_BS 1024
#define HIST_BLOCKS 1024

__device__ __forceinline__ unsigned enc_f(float f) {
    unsigned u = __float_as_uint(f);
    return (u & 0x80000000u) ? ~u : (u | 0x80000000u);
}
__device__ __forceinline__ float dec_f(unsigned u) {
    u = (u & 0x80000000u) ? (u & 0x7fffffffu) : ~u;
    return __uint_as_float(u);
}
__device__ __forceinline__ unsigned short f2bf(float x) {  // round-to-nearest-even
    unsigned u = __float_as_uint(x);
    return (unsigned short)((u + 0x7fffu + ((u >> 16) & 1u)) >> 16);
}

// ---- prep: WT[d][o] = W_src[o][d];  wc[h][d] = sum_f a_trg[h,f]*W_trg[h*16+f][d]
__global__ void prep_kernel(const float* __restrict__ W_src,
                            const float* __restrict__ W_trg,
                            const float* __restrict__ a_trg,
                            float* __restrict__ WT, float* __restrict__ wc) {
    int t = blockIdx.x * blockDim.x + threadIdx.x;
    if (t < D * D) {
        int o = t >> 7, d = t & 127;
        WT[d * D + o] = W_src[t];
    } else if (t < D * D + NH * D) {
        int u = t - D * D;
        int h = u >> 7, d = u & 127;
        float acc = 0.f;
#pragma unroll
        for (int f = 0; f < FOUT; ++f)
            acc += a_trg[h * FOUT + f] * W_trg[(h * FOUT + f) * D + d];
        wc[h * D + d] = acc;
    }
}

// ---- fused: blocks [0,PB) projection (proj bf16, s_src, s_trg, maxes);
//             blocks [PB,..) target histogram over edges
__global__ __launch_bounds__(256) void projhist_kernel(
    const float* __restrict__ src, const float* __restrict__ trg,
    const float* __restrict__ WT, const float* __restrict__ a_src,
    const float* __restrict__ wc, const int* __restrict__ ei,
    unsigned short* __restrict__ projb,
    float* __restrict__ s_src, float* __restrict__ s_trg,
    unsigned* __restrict__ gmax_enc, int* __restrict__ counts,
    int N, int E, int PB) {
    int tid = threadIdx.x;

    if (blockIdx.x >= PB) {   // -------- histogram part
        for (int e = (blockIdx.x - PB) * 256 + tid; e < E; e += HIST_BLOCKS * 256)
            atomicAdd(counts + ei[E + e], 1);
        return;
    }

    // -------- projection part
    int n0 = blockIdx.x * TNODES;
    __shared__ float st[TNODES][D];
    __shared__ float tt[TNODES][D + 4];
    __shared__ float red[256];

    {
        const float4* src4 = (const float4*)(src + (size_t)n0 * D);
        const float4* trg4 = (const float4*)(trg + (size_t)n0 * D);
        for (int i = tid; i < TNODES * 32; i += 256) {
            ((float4*)st)[i] = src4[i];
            int n = i >> 5, c = i & 31;
            *((float4*)&tt[n][c * 4]) = trg4[i];
        }
    }
    __syncthreads();

    int q = tid & 31;    // feature quad: features 4q..4q+3
    int slot = tid >> 5; // nodes slot*4..slot*4+3
    float acc[4][4] = {{0.f}};

    for (int d = 0; d < D; d += 4) {
        float4 w[4];
#pragma unroll
        for (int k = 0; k < 4; ++k)
            w[k] = *((const float4*)(WT + (d + k) * D + 4 * q));
#pragma unroll
        for (int r = 0; r < 4; ++r) {
            float4 sv = *((const float4*)&st[slot * 4 + r][d]);
            float sa[4] = {sv.x, sv.y, sv.z, sv.w};
#pragma unroll
            for (int k = 0; k < 4; ++k) {
                acc[r][0] += sa[k] * w[k].x;
                acc[r][1] += sa[k] * w[k].y;
                acc[r][2] += sa[k] * w[k].z;
                acc[r][3] += sa[k] * w[k].w;
            }
        }
    }

    float lmax = -1e30f;
    float4 av = ((const float4*)a_src)[q];
#pragma unroll
    for (int r = 0; r < 4; ++r) {
        int n = slot * 4 + r;
        ushort4 pk;
        pk.x = f2bf(acc[r][0]); pk.y = f2bf(acc[r][1]);
        pk.z = f2bf(acc[r][2]); pk.w = f2bf(acc[r][3]);
        *((ushort4*)(projb + ((size_t)(n0 + n)) * D + 4 * q)) = pk;
        float p = acc[r][0] * av.x + acc[r][1] * av.y + acc[r][2] * av.z + acc[r][3] * av.w;
        p += __shfl_xor(p, 1);
        p += __shfl_xor(p, 2);
        if ((q & 3) == 0) s_src[(size_t)(n0 + n) * NH + (q >> 2)] = p;
        lmax = fmaxf(lmax, p);
    }

    int n2 = tid >> 3, h2 = tid & 7;
    float dot = 0.f;
    for (int c = 0; c < 32; ++c) {
        float4 tv = *((const float4*)&tt[n2][c * 4]);
        float4 wv = ((const float4*)(wc + h2 * D))[c];
        dot += tv.x * wv.x + tv.y * wv.y + tv.z * wv.z + tv.w * wv.w;
    }
    s_trg[(size_t)(n0 + n2) * NH + h2] = dot;

    red[tid] = lmax;
    __syncthreads();
    for (int s = 128; s; s >>= 1) {
        if (tid < s) red[tid] = fmaxf(red[tid], red[tid + s]);
        __syncthreads();
    }
    if (tid == 0) atomicMax(gmax_enc + 0, enc_f(red[0]));
    __syncthreads();
    red[tid] = dot;
    __syncthreads();
    for (int s = 128; s; s >>= 1) {
        if (tid < s) red[tid] = fmaxf(red[tid], red[tid + s]);
        __syncthreads();
    }
    if (tid == 0) atomicMax(gmax_enc + 1, enc_f(red[0]));
}

// ---- scans (cursor = exclusive offsets); scan2 also finalizes the global max
__global__ void scan1_kernel(const int* __restrict__ counts, int* __restrict__ cursor,
                             int* __restrict__ bsum, int N) {
    __shared__ int tmp[SCAN_BS];
    int t = threadIdx.x, g = blockIdx.x * SCAN_BS + t;
    int v = (g < N) ? counts[g] : 0;
    tmp[t] = v;
    __syncthreads();
    for (int off = 1; off < SCAN_BS; off <<= 1) {
        int x = (t >= off) ? tmp[t - off] : 0;
        __syncthreads();
        tmp[t] += x;
        __syncthreads();
    }
    if (g < N) cursor[g] = tmp[t] - v;
    if (t == SCAN_BS - 1) bsum[blockIdx.x] = tmp[t];
}
__global__ void scan2_kernel(int* __restrict__ bsum, int nb,
                             const unsigned* __restrict__ ge, float* __restrict__ gmaxf) {
    __shared__ int tmp[128];
    int t = threadIdx.x;
    int v = (t < nb) ? bsum[t] : 0;
    tmp[t] = v;
    __syncthreads();
    for (int off = 1; off < 128; off <<= 1) {
        int x = (t >= off) ? tmp[t - off] : 0;
        __syncthreads();
        tmp[t] += x;
        __syncthreads();
    }
    if (t < nb) bsum[t] = tmp[t] - v;
    if (t == 0) gmaxf[0] = dec_f(ge[0]) + dec_f(ge[1]);  // M >= true max; cancels
}
__global__ void scan3_kernel(int* __restrict__ cursor, const int* __restrict__ bsum, int N) {
    int g = blockIdx.x * SCAN_BS + threadIdx.x;
    if (g < N) cursor[g] += bsum[blockIdx.x];
}

// ---- scatter edges into CSR buckets (2 edges/thread, int2 reads)
__global__ void scatter_kernel(const int* __restrict__ ei, int* __restrict__ cursor,
                               int* __restrict__ perm_src, int E) {
    int e = 2 * (blockIdx.x * blockDim.x + threadIdx.x);
    if (e + 1 < E) {
        int2 s2 = *((const int2*)(ei + e));
        int2 t2 = *((const int2*)(ei + E + e));
        perm_src[atomicAdd(cursor + t2.x, 1)] = s2.x;
        perm_src[atomicAdd(cursor + t2.y, 1)] = s2.y;
    } else if (e < E) {
        int si = ei[e], ti = ei[E + e];
        perm_src[atomicAdd(cursor + ti, 1)] = si;
    }
}

// ---- per-target aggregation: bf16 gather, atomic-free, fused normalize
__global__ __launch_bounds__(64) void agg_kernel(
    const int* __restrict__ cursor_end, const int* __restrict__ counts,
    const int* __restrict__ perm_src,
    const float* __restrict__ s_src, const float* __restrict__ s_trg,
    const unsigned short* __restrict__ projb, const float* __restrict__ gmaxf,
    float* __restrict__ out) {
    int n = blockIdx.x;
    int t = threadIdx.x;     // 0..63, owns features 2t, 2t+1
    int h = t >> 3;
    int cnt = counts[n];
    int start = cursor_end[n] - cnt;
    float M = gmaxf[0];
    __shared__ float stg_sh[NH];
    __shared__ int sie[64];
    __shared__ float wls[64][NH + 1];
    if (t < NH) stg_sh[t] = s_trg[(size_t)n * NH + t];

    const unsigned* p2 = (const unsigned*)projb;   // bf16x2, row stride 64
    float acc0 = 0.f, acc1 = 0.f, wsum = 0.f;

    for (int base = 0; base < cnt; base += 64) {
        int idx = base + t;
        __syncthreads();
        if (idx < cnt) {
            int si = perm_src[start + idx];
            sie[t] = si;
            const float* ps = s_src + (size_t)si * NH;
#pragma unroll
            for (int hh = 0; hh < NH; ++hh) {
                float sc = ps[hh] + stg_sh[hh];
                sc = sc > 0.f ? sc : NEG_SLOPE * sc;
                wls[t][hh] = __expf(sc - M);
            }
        }
        __syncthreads();
        int m = min(64, cnt - base);
#pragma unroll 4
        for (int j = 0; j < m; ++j) {
            int si = sie[j];
            float w = wls[j][h];
            unsigned pv = p2[(size_t)si * 64 + t];
            float lo = __uint_as_float(pv << 16);
            float hi = __uint_as_float(pv & 0xffff0000u);
            wsum += w;
            acc0 += w * lo;
            acc1 += w * hi;
        }
    }
    float inv = 1.f / (wsum + 1e-16f);
    *((float2*)(out + (size_t)n * D + 2 * t)) = make_float2(acc0 * inv, acc1 * inv);
}

extern "C" void kernel_launch(void* const* d_in, const int* in_sizes, int n_in,
                              void* d_out, int out_size, void* d_ws, size_t ws_size,
                              hipStream_t stream) {
    const float* trg   = (const float*)d_in[0];
    const float* src   = (const float*)d_in[1];
    const int*   ei    = (const int*)d_in[2];
    const float* W_trg = (const float*)d_in[3];
    const float* W_src = (const float*)d_in[4];
    const float* a_src = (const float*)d_in[5];
    const float* a_trg = (const float*)d_in[6];
    float* out = (float*)d_out;

    const int N = in_sizes[0] / D;   // 100000
    const int E = in_sizes[2] / 2;   // 1600000

    float* ws       = (float*)d_ws;
    float* WT       = ws;                          // 128*128
    float* wc       = WT + D * D;                  // 8*128
    unsigned* gmaxe = (unsigned*)(wc + NH * D);    // 2 (pad 4)
    float* gmaxf    = (float*)(gmaxe + 4);         // 1 (pad 4)
    float* s_src    = gmaxf + 4;                   // N*8
    float* s_trg    = s_src + (size_t)N * NH;      // N*8
    int*   counts   = (int*)(s_trg + (size_t)N * NH);  // N
    int*   cursor   = counts + N;                  // N
    int*   bsum     = cursor + N;                  // 128
    int*   perm_src = bsum + 128;                  // E
    unsigned short* projb = (unsigned short*)(perm_src + E);  // N*128 bf16

    const int NB = (N + SCAN_BS - 1) / SCAN_BS;    // 98
    const int PB = N / TNODES;                     // 3125

    hipMemsetAsync(counts, 0, (size_t)N * sizeof(int), stream);
    hipMemsetAsync(gmaxe, 0, 4 * sizeof(unsigned), stream);

    prep_kernel<<<(D * D + NH * D + 255) / 256, 256, 0, stream>>>(W_src, W_trg, a_trg, WT, wc);
    projhist_kernel<<<PB + HIST_BLOCKS, 256, 0, stream>>>(
        src, trg, WT, a_src, wc, ei, projb, s_src, s_trg, gmaxe, counts, N, E, PB);
    scan1_kernel<<<NB, SCAN_BS, 0, stream>>>(counts, cursor, bsum, N);
    scan2_kernel<<<1, 128, 0, stream>>>(bsum, NB, gmaxe, gmaxf);
    scan3_kernel<<<NB, SCAN_BS, 0, stream>>>(cursor, bsum, N);
    scatter_kernel<<<(E / 2 + 255) / 256, 256, 0, stream>>>(ei, cursor, perm_src, E);
    agg_kernel<<<N, 64, 0, stream>>>(cursor, counts, perm_src,
                                     s_src, s_trg, projb, gmaxf, out);
}

// Round 5
// 416.067 us; speedup vs baseline: 3.6597x; 1.0035x over previous
//
#include <hip/hip_runtime.h>

#define D 128
#define NH 8
#define FOUT 16
#define NEG_SLOPE 0.2f
#define TNODES 32
#define SCAN_BS 1024
#define HIST_BLOCKS 1024

__device__ __forceinline__ unsigned enc_f(float f) {
    unsigned u = __float_as_uint(f);
    return (u & 0x80000000u) ? ~u : (u | 0x80000000u);
}
__device__ __forceinline__ float dec_f(unsigned u) {
    u = (u & 0x80000000u) ? (u & 0x7fffffffu) : ~u;
    return __uint_as_float(u);
}
__device__ __forceinline__ unsigned short f2bf(float x) {  // round-to-nearest-even
    unsigned u = __float_as_uint(x);
    return (unsigned short)((u + 0x7fffu + ((u >> 16) & 1u)) >> 16);
}

// ---- prep: WT[d][o] = W_src[o][d];  wc[h][d] = sum_f a_trg[h,f]*W_trg[h*16+f][d]
__global__ void prep_kernel(const float* __restrict__ W_src,
                            const float* __restrict__ W_trg,
                            const float* __restrict__ a_trg,
                            float* __restrict__ WT, float* __restrict__ wc) {
    int t = blockIdx.x * blockDim.x + threadIdx.x;
    if (t < D * D) {
        int o = t >> 7, d = t & 127;
        WT[d * D + o] = W_src[t];
    } else if (t < D * D + NH * D) {
        int u = t - D * D;
        int h = u >> 7, d = u & 127;
        float acc = 0.f;
#pragma unroll
        for (int f = 0; f < FOUT; ++f)
            acc += a_trg[h * FOUT + f] * W_trg[(h * FOUT + f) * D + d];
        wc[h * D + d] = acc;
    }
}

// ---- fused: blocks [0,PB): projection (time-shared LDS tile: trg phase then src GEMM)
//             blocks [PB,..): target histogram over edges
__global__ __launch_bounds__(256) void projhist_kernel(
    const float* __restrict__ src, const float* __restrict__ trg,
    const float* __restrict__ WT, const float* __restrict__ a_src,
    const float* __restrict__ wc, const int* __restrict__ ei,
    unsigned short* __restrict__ projb,
    float* __restrict__ s_src, float* __restrict__ s_trg,
    unsigned* __restrict__ gmax_enc, int* __restrict__ counts,
    int N, int E, int PB) {
    int tid = threadIdx.x;

    if (blockIdx.x >= PB) {   // -------- histogram part
        for (int e = (blockIdx.x - PB) * 256 + tid; e < E; e += HIST_BLOCKS * 256)
            atomicAdd(counts + ei[E + e], 1);
        return;
    }

    // -------- projection part
    int n0 = blockIdx.x * TNODES;
    __shared__ float tile[TNODES][D + 4];   // time-shared: trg, then src
    __shared__ float red[256];

    // phase 1: stage trg tile
    {
        const float4* trg4 = (const float4*)(trg + (size_t)n0 * D);
        for (int i = tid; i < TNODES * 32; i += 256) {
            int n = i >> 5, c = i & 31;
            *((float4*)&tile[n][c * 4]) = trg4[i];
        }
    }
    __syncthreads();

    // s_trg: thread -> (node = tid>>3, head = tid&7)
    int n2 = tid >> 3, h2 = tid & 7;
    float dot = 0.f;
    for (int c = 0; c < 32; ++c) {
        float4 tv = *((const float4*)&tile[n2][c * 4]);
        float4 wv = ((const float4*)(wc + h2 * D))[c];
        dot += tv.x * wv.x + tv.y * wv.y + tv.z * wv.z + tv.w * wv.w;
    }
    s_trg[(size_t)(n0 + n2) * NH + h2] = dot;

    red[tid] = dot;
    __syncthreads();
    for (int s = 128; s; s >>= 1) {
        if (tid < s) red[tid] = fmaxf(red[tid], red[tid + s]);
        __syncthreads();
    }
    if (tid == 0) atomicMax(gmax_enc + 1, enc_f(red[0]));
    __syncthreads();

    // phase 2: restage src into the same tile
    {
        const float4* src4 = (const float4*)(src + (size_t)n0 * D);
        for (int i = tid; i < TNODES * 32; i += 256) {
            int n = i >> 5, c = i & 31;
            *((float4*)&tile[n][c * 4]) = src4[i];
        }
    }
    __syncthreads();

    int q = tid & 31;    // feature quad: features 4q..4q+3
    int slot = tid >> 5; // nodes slot*4..slot*4+3
    float acc[4][4] = {{0.f}};

    for (int d = 0; d < D; d += 4) {
        float4 w[4];
#pragma unroll
        for (int k = 0; k < 4; ++k)
            w[k] = *((const float4*)(WT + (d + k) * D + 4 * q));
#pragma unroll
        for (int r = 0; r < 4; ++r) {
            float4 sv = *((const float4*)&tile[slot * 4 + r][d]);
            float sa[4] = {sv.x, sv.y, sv.z, sv.w};
#pragma unroll
            for (int k = 0; k < 4; ++k) {
                acc[r][0] += sa[k] * w[k].x;
                acc[r][1] += sa[k] * w[k].y;
                acc[r][2] += sa[k] * w[k].z;
                acc[r][3] += sa[k] * w[k].w;
            }
        }
    }

    float lmax = -1e30f;
    float4 av = ((const float4*)a_src)[q];
#pragma unroll
    for (int r = 0; r < 4; ++r) {
        int n = slot * 4 + r;
        ushort4 pk;
        pk.x = f2bf(acc[r][0]); pk.y = f2bf(acc[r][1]);
        pk.z = f2bf(acc[r][2]); pk.w = f2bf(acc[r][3]);
        *((ushort4*)(projb + ((size_t)(n0 + n)) * D + 4 * q)) = pk;
        float p = acc[r][0] * av.x + acc[r][1] * av.y + acc[r][2] * av.z + acc[r][3] * av.w;
        p += __shfl_xor(p, 1);
        p += __shfl_xor(p, 2);
        if ((q & 3) == 0) s_src[(size_t)(n0 + n) * NH + (q >> 2)] = p;
        lmax = fmaxf(lmax, p);
    }

    red[tid] = lmax;
    __syncthreads();
    for (int s = 128; s; s >>= 1) {
        if (tid < s) red[tid] = fmaxf(red[tid], red[tid + s]);
        __syncthreads();
    }
    if (tid == 0) atomicMax(gmax_enc + 0, enc_f(red[0]));
}

// ---- scans (cursor = exclusive offsets); scan2 also finalizes the global max
__global__ void scan1_kernel(const int* __restrict__ counts, int* __restrict__ cursor,
                             int* __restrict__ bsum, int N) {
    __shared__ int tmp[SCAN_BS];
    int t = threadIdx.x, g = blockIdx.x * SCAN_BS + t;
    int v = (g < N) ? counts[g] : 0;
    tmp[t] = v;
    __syncthreads();
    for (int off = 1; off < SCAN_BS; off <<= 1) {
        int x = (t >= off) ? tmp[t - off] : 0;
        __syncthreads();
        tmp[t] += x;
        __syncthreads();
    }
    if (g < N) cursor[g] = tmp[t] - v;
    if (t == SCAN_BS - 1) bsum[blockIdx.x] = tmp[t];
}
__global__ void scan2_kernel(int* __restrict__ bsum, int nb,
                             const unsigned* __restrict__ ge, float* __restrict__ gmaxf) {
    __shared__ int tmp[128];
    int t = threadIdx.x;
    int v = (t < nb) ? bsum[t] : 0;
    tmp[t] = v;
    __syncthreads();
    for (int off = 1; off < 128; off <<= 1) {
        int x = (t >= off) ? tmp[t - off] : 0;
        __syncthreads();
        tmp[t] += x;
        __syncthreads();
    }
    if (t < nb) bsum[t] = tmp[t] - v;
    if (t == 0) gmaxf[0] = dec_f(ge[0]) + dec_f(ge[1]);  // M >= true max; cancels
}
__global__ void scan3_kernel(int* __restrict__ cursor, const int* __restrict__ bsum, int N) {
    int g = blockIdx.x * SCAN_BS + threadIdx.x;
    if (g < N) cursor[g] += bsum[blockIdx.x];
}

// ---- scatter edges into CSR buckets (2 edges/thread, int2 reads)
__global__ void scatter_kernel(const int* __restrict__ ei, int* __restrict__ cursor,
                               int* __restrict__ perm_src, int E) {
    int e = 2 * (blockIdx.x * blockDim.x + threadIdx.x);
    if (e + 1 < E) {
        int2 s2 = *((const int2*)(ei + e));
        int2 t2 = *((const int2*)(ei + E + e));
        perm_src[atomicAdd(cursor + t2.x, 1)] = s2.x;
        perm_src[atomicAdd(cursor + t2.y, 1)] = s2.y;
    } else if (e < E) {
        int si = ei[e], ti = ei[E + e];
        perm_src[atomicAdd(cursor + ti, 1)] = si;
    }
}

// ---- per-target aggregation: bf16 gather, atomic-free, fused normalize
__global__ __launch_bounds__(64) void agg_kernel(
    const int* __restrict__ cursor_end, const int* __restrict__ counts,
    const int* __restrict__ perm_src,
    const float* __restrict__ s_src, const float* __restrict__ s_trg,
    const unsigned short* __restrict__ projb, const float* __restrict__ gmaxf,
    float* __restrict__ out) {
    int n = blockIdx.x;
    int t = threadIdx.x;     // 0..63, owns features 2t, 2t+1
    int h = t >> 3;
    int cnt = counts[n];
    int start = cursor_end[n] - cnt;
    float M = gmaxf[0];
    __shared__ float stg_sh[NH];
    __shared__ int sie[64];
    __shared__ float wls[64][NH + 1];
    if (t < NH) stg_sh[t] = s_trg[(size_t)n * NH + t];

    const unsigned* p2 = (const unsigned*)projb;   // bf16x2, row stride 64
    float acc0 = 0.f, acc1 = 0.f, wsum = 0.f;

    for (int base = 0; base < cnt; base += 64) {
        int idx = base + t;
        __syncthreads();
        if (idx < cnt) {
            int si = perm_src[start + idx];
            sie[t] = si;
            const float* ps = s_src + (size_t)si * NH;
#pragma unroll
            for (int hh = 0; hh < NH; ++hh) {
                float sc = ps[hh] + stg_sh[hh];
                sc = sc > 0.f ? sc : NEG_SLOPE * sc;
                wls[t][hh] = __expf(sc - M);
            }
        }
        __syncthreads();
        int m = min(64, cnt - base);
#pragma unroll 4
        for (int j = 0; j < m; ++j) {
            int si = sie[j];
            float w = wls[j][h];
            unsigned pv = p2[(size_t)si * 64 + t];
            float lo = __uint_as_float(pv << 16);
            float hi = __uint_as_float(pv & 0xffff0000u);
            wsum += w;
            acc0 += w * lo;
            acc1 += w * hi;
        }
    }
    float inv = 1.f / (wsum + 1e-16f);
    *((float2*)(out + (size_t)n * D + 2 * t)) = make_float2(acc0 * inv, acc1 * inv);
}

extern "C" void kernel_launch(void* const* d_in, const int* in_sizes, int n_in,
                              void* d_out, int out_size, void* d_ws, size_t ws_size,
                              hipStream_t stream) {
    const float* trg   = (const float*)d_in[0];
    const float* src   = (const float*)d_in[1];
    const int*   ei    = (const int*)d_in[2];
    const float* W_trg = (const float*)d_in[3];
    const float* W_src = (const float*)d_in[4];
    const float* a_src = (const float*)d_in[5];
    const float* a_trg = (const float*)d_in[6];
    float* out = (float*)d_out;

    const int N = in_sizes[0] / D;   // 100000
    const int E = in_sizes[2] / 2;   // 1600000

    float* ws       = (float*)d_ws;
    float* WT       = ws;                          // 128*128
    float* wc       = WT + D * D;                  // 8*128
    unsigned* gmaxe = (unsigned*)(wc + NH * D);    // 2 (pad 4)
    float* gmaxf    = (float*)(gmaxe + 4);         // 1 (pad 4)
    float* s_src    = gmaxf + 4;                   // N*8
    float* s_trg    = s_src + (size_t)N * NH;      // N*8
    int*   counts   = (int*)(s_trg + (size_t)N * NH);  // N
    int*   cursor   = counts + N;                  // N
    int*   bsum     = cursor + N;                  // 128
    int*   perm_src = bsum + 128;                  // E
    unsigned short* projb = (unsigned short*)(perm_src + E);  // N*128 bf16

    const int NB = (N + SCAN_BS - 1) / SCAN_BS;    // 98
    const int PB = N / TNODES;                     // 3125

    hipMemsetAsync(counts, 0, (size_t)N * sizeof(int), stream);
    hipMemsetAsync(gmaxe, 0, 4 * sizeof(unsigned), stream);

    prep_kernel<<<(D * D + NH * D + 255) / 256, 256, 0, stream>>>(W_src, W_trg, a_trg, WT, wc);
    projhist_kernel<<<PB + HIST_BLOCKS, 256, 0, stream>>>(
        src, trg, WT, a_src, wc, ei, projb, s_src, s_trg, gmaxe, counts, N, E, PB);
    scan1_kernel<<<NB, SCAN_BS, 0, stream>>>(counts, cursor, bsum, N);
    scan2_kernel<<<1, 128, 0, stream>>>(bsum, NB, gmaxe, gmaxf);
    scan3_kernel<<<NB, SCAN_BS, 0, stream>>>(cursor, bsum, N);
    scatter_kernel<<<(E / 2 + 255) / 256, 256, 0, stream>>>(ei, cursor, perm_src, E);
    agg_kernel<<<N, 64, 0, stream>>>(cursor, counts, perm_src,
                                     s_src, s_trg, projb, gmaxf, out);
}

// Round 6
// 403.548 us; speedup vs baseline: 3.7732x; 1.0310x over previous
//
#include <hip/hip_runtime.h>

#define D 128
#define NH 8
#define FOUT 16
#define NEG_SLOPE 0.2f
#define TNODES 64
#define SCAN_BS 1024
#define HIST_BLOCKS 1024

__device__ __forceinline__ unsigned enc_f(float f) {
    unsigned u = __float_as_uint(f);
    return (u & 0x80000000u) ? ~u : (u | 0x80000000u);
}
__device__ __forceinline__ float dec_f(unsigned u) {
    u = (u & 0x80000000u) ? (u & 0x7fffffffu) : ~u;
    return __uint_as_float(u);
}
__device__ __forceinline__ unsigned short f2bf(float x) {  // round-to-nearest-even
    unsigned u = __float_as_uint(x);
    return (unsigned short)((u + 0x7fffu + ((u >> 16) & 1u)) >> 16);
}

// ---- prep: WT[d][o] = W_src[o][d];  wc[h][d] = sum_f a_trg[h,f]*W_trg[h*16+f][d]
__global__ void prep_kernel(const float* __restrict__ W_src,
                            const float* __restrict__ W_trg,
                            const float* __restrict__ a_trg,
                            float* __restrict__ WT, float* __restrict__ wc) {
    int t = blockIdx.x * blockDim.x + threadIdx.x;
    if (t < D * D) {
        int o = t >> 7, d = t & 127;
        WT[d * D + o] = W_src[t];
    } else if (t < D * D + NH * D) {
        int u = t - D * D;
        int h = u >> 7, d = u & 127;
        float acc = 0.f;
#pragma unroll
        for (int f = 0; f < FOUT; ++f)
            acc += a_trg[h * FOUT + f] * W_trg[(h * FOUT + f) * D + d];
        wc[h * D + d] = acc;
    }
}

// ---- fused: blocks [0,PB): projection, 64 nodes/block, time-shared LDS tile
//             blocks [PB,..): target histogram over edges
__global__ __launch_bounds__(256) void projhist_kernel(
    const float* __restrict__ src, const float* __restrict__ trg,
    const float* __restrict__ WT, const float* __restrict__ a_src,
    const float* __restrict__ wc, const int* __restrict__ ei,
    unsigned short* __restrict__ projb,
    float* __restrict__ s_src, float* __restrict__ s_trg,
    unsigned* __restrict__ gmax_enc, int* __restrict__ counts,
    int N, int E, int PB) {
    int tid = threadIdx.x;

    if (blockIdx.x >= PB) {   // -------- histogram part
        for (int e = (blockIdx.x - PB) * 256 + tid; e < E; e += HIST_BLOCKS * 256)
            atomicAdd(counts + ei[E + e], 1);
        return;
    }

    // -------- projection part
    int n0 = blockIdx.x * TNODES;
    int nodes = min(TNODES, N - n0);
    int nwords = nodes * 32;                // float4 chunks of valid data
    __shared__ float tile[TNODES][D + 4];   // time-shared: trg, then src
    __shared__ float red[256];

    // phase 1: stage trg tile (zero-fill tail)
    {
        const float4* trg4 = (const float4*)(trg + (size_t)n0 * D);
        for (int i = tid; i < TNODES * 32; i += 256) {
            int n = i >> 5, c = i & 31;
            float4 v = (i < nwords) ? trg4[i] : make_float4(0.f, 0.f, 0.f, 0.f);
            *((float4*)&tile[n][c * 4]) = v;
        }
    }
    __syncthreads();

    // s_trg: 2 reps, thread -> (node = rep*32 + tid>>3, head = tid&7)
    float tmax = -1e30f;
    int h2 = tid & 7;
#pragma unroll
    for (int rep = 0; rep < 2; ++rep) {
        int n2 = rep * 32 + (tid >> 3);
        float dot = 0.f;
        for (int c = 0; c < 32; ++c) {
            float4 tv = *((const float4*)&tile[n2][c * 4]);
            float4 wv = ((const float4*)(wc + h2 * D))[c];
            dot += tv.x * wv.x + tv.y * wv.y + tv.z * wv.z + tv.w * wv.w;
        }
        if (n2 < nodes) {
            s_trg[(size_t)(n0 + n2) * NH + h2] = dot;
            tmax = fmaxf(tmax, dot);
        }
    }
    red[tid] = tmax;
    __syncthreads();
    for (int s = 128; s; s >>= 1) {
        if (tid < s) red[tid] = fmaxf(red[tid], red[tid + s]);
        __syncthreads();
    }
    if (tid == 0) atomicMax(gmax_enc + 1, enc_f(red[0]));
    __syncthreads();

    // phase 2: restage src into the same tile (zero-fill tail)
    {
        const float4* src4 = (const float4*)(src + (size_t)n0 * D);
        for (int i = tid; i < TNODES * 32; i += 256) {
            int n = i >> 5, c = i & 31;
            float4 v = (i < nwords) ? src4[i] : make_float4(0.f, 0.f, 0.f, 0.f);
            *((float4*)&tile[n][c * 4]) = v;
        }
    }
    __syncthreads();

    int q = tid & 31;    // feature quad: features 4q..4q+3
    int slot = tid >> 5; // rows slot*8 .. slot*8+7
    float acc[8][4] = {{0.f}};

    for (int d = 0; d < D; d += 8) {
        float4 w[8];
#pragma unroll
        for (int k = 0; k < 8; ++k)
            w[k] = *((const float4*)(WT + (d + k) * D + 4 * q));
#pragma unroll
        for (int r = 0; r < 8; ++r) {
            float4 s0 = *((const float4*)&tile[slot * 8 + r][d]);
            float4 s1 = *((const float4*)&tile[slot * 8 + r][d + 4]);
            float sa[8] = {s0.x, s0.y, s0.z, s0.w, s1.x, s1.y, s1.z, s1.w};
#pragma unroll
            for (int k = 0; k < 8; ++k) {
                acc[r][0] += sa[k] * w[k].x;
                acc[r][1] += sa[k] * w[k].y;
                acc[r][2] += sa[k] * w[k].z;
                acc[r][3] += sa[k] * w[k].w;
            }
        }
    }

    float lmax = -1e30f;
    float4 av = ((const float4*)a_src)[q];
#pragma unroll
    for (int r = 0; r < 8; ++r) {
        int n = slot * 8 + r;
        bool valid = n < nodes;
        if (valid) {
            ushort4 pk;
            pk.x = f2bf(acc[r][0]); pk.y = f2bf(acc[r][1]);
            pk.z = f2bf(acc[r][2]); pk.w = f2bf(acc[r][3]);
            *((ushort4*)(projb + ((size_t)(n0 + n)) * D + 4 * q)) = pk;
        }
        float p = acc[r][0] * av.x + acc[r][1] * av.y + acc[r][2] * av.z + acc[r][3] * av.w;
        p += __shfl_xor(p, 1);
        p += __shfl_xor(p, 2);
        if (valid) {
            if ((q & 3) == 0) s_src[(size_t)(n0 + n) * NH + (q >> 2)] = p;
            lmax = fmaxf(lmax, p);
        }
    }

    red[tid] = lmax;
    __syncthreads();
    for (int s = 128; s; s >>= 1) {
        if (tid < s) red[tid] = fmaxf(red[tid], red[tid + s]);
        __syncthreads();
    }
    if (tid == 0) atomicMax(gmax_enc + 0, enc_f(red[0]));
}

// ---- scans (cursor = exclusive offsets); scan2 also finalizes the global max
__global__ void scan1_kernel(const int* __restrict__ counts, int* __restrict__ cursor,
                             int* __restrict__ bsum, int N) {
    __shared__ int tmp[SCAN_BS];
    int t = threadIdx.x, g = blockIdx.x * SCAN_BS + t;
    int v = (g < N) ? counts[g] : 0;
    tmp[t] = v;
    __syncthreads();
    for (int off = 1; off < SCAN_BS; off <<= 1) {
        int x = (t >= off) ? tmp[t - off] : 0;
        __syncthreads();
        tmp[t] += x;
        __syncthreads();
    }
    if (g < N) cursor[g] = tmp[t] - v;
    if (t == SCAN_BS - 1) bsum[blockIdx.x] = tmp[t];
}
__global__ void scan2_kernel(int* __restrict__ bsum, int nb,
                             const unsigned* __restrict__ ge, float* __restrict__ gmaxf) {
    __shared__ int tmp[128];
    int t = threadIdx.x;
    int v = (t < nb) ? bsum[t] : 0;
    tmp[t] = v;
    __syncthreads();
    for (int off = 1; off < 128; off <<= 1) {
        int x = (t >= off) ? tmp[t - off] : 0;
        __syncthreads();
        tmp[t] += x;
        __syncthreads();
    }
    if (t < nb) bsum[t] = tmp[t] - v;
    if (t == 0) gmaxf[0] = dec_f(ge[0]) + dec_f(ge[1]);  // M >= true max; cancels
}
__global__ void scan3_kernel(int* __restrict__ cursor, const int* __restrict__ bsum, int N) {
    int g = blockIdx.x * SCAN_BS + threadIdx.x;
    if (g < N) cursor[g] += bsum[blockIdx.x];
}

// ---- scatter edges into CSR buckets (2 edges/thread, int2 reads)
__global__ void scatter_kernel(const int* __restrict__ ei, int* __restrict__ cursor,
                               int* __restrict__ perm_src, int E) {
    int e = 2 * (blockIdx.x * blockDim.x + threadIdx.x);
    if (e + 1 < E) {
        int2 s2 = *((const int2*)(ei + e));
        int2 t2 = *((const int2*)(ei + E + e));
        perm_src[atomicAdd(cursor + t2.x, 1)] = s2.x;
        perm_src[atomicAdd(cursor + t2.y, 1)] = s2.y;
    } else if (e < E) {
        int si = ei[e], ti = ei[E + e];
        perm_src[atomicAdd(cursor + ti, 1)] = si;
    }
}

// ---- per-target aggregation: bf16 gather, atomic-free, fused normalize
__global__ __launch_bounds__(64) void agg_kernel(
    const int* __restrict__ cursor_end, const int* __restrict__ counts,
    const int* __restrict__ perm_src,
    const float* __restrict__ s_src, const float* __restrict__ s_trg,
    const unsigned short* __restrict__ projb, const float* __restrict__ gmaxf,
    float* __restrict__ out) {
    int n = blockIdx.x;
    int t = threadIdx.x;     // 0..63, owns features 2t, 2t+1
    int h = t >> 3;
    int cnt = counts[n];
    int start = cursor_end[n] - cnt;
    float M = gmaxf[0];
    __shared__ float stg_sh[NH];
    __shared__ int sie[64];
    __shared__ float wls[64][NH + 1];
    if (t < NH) stg_sh[t] = s_trg[(size_t)n * NH + t];

    const unsigned* p2 = (const unsigned*)projb;   // bf16x2, row stride 64
    float acc0 = 0.f, acc1 = 0.f, wsum = 0.f;

    for (int base = 0; base < cnt; base += 64) {
        int idx = base + t;
        __syncthreads();
        if (idx < cnt) {
            int si = perm_src[start + idx];
            sie[t] = si;
            const float* ps = s_src + (size_t)si * NH;
#pragma unroll
            for (int hh = 0; hh < NH; ++hh) {
                float sc = ps[hh] + stg_sh[hh];
                sc = sc > 0.f ? sc : NEG_SLOPE * sc;
                wls[t][hh] = __expf(sc - M);
            }
        }
        __syncthreads();
        int m = min(64, cnt - base);
#pragma unroll 4
        for (int j = 0; j < m; ++j) {
            int si = sie[j];
            float w = wls[j][h];
            unsigned pv = p2[(size_t)si * 64 + t];
            float lo = __uint_as_float(pv << 16);
            float hi = __uint_as_float(pv & 0xffff0000u);
            wsum += w;
            acc0 += w * lo;
            acc1 += w * hi;
        }
    }
    float inv = 1.f / (wsum + 1e-16f);
    *((float2*)(out + (size_t)n * D + 2 * t)) = make_float2(acc0 * inv, acc1 * inv);
}

extern "C" void kernel_launch(void* const* d_in, const int* in_sizes, int n_in,
                              void* d_out, int out_size, void* d_ws, size_t ws_size,
                              hipStream_t stream) {
    const float* trg   = (const float*)d_in[0];
    const float* src   = (const float*)d_in[1];
    const int*   ei    = (const int*)d_in[2];
    const float* W_trg = (const float*)d_in[3];
    const float* W_src = (const float*)d_in[4];
    const float* a_src = (const float*)d_in[5];
    const float* a_trg = (const float*)d_in[6];
    float* out = (float*)d_out;

    const int N = in_sizes[0] / D;   // 100000
    const int E = in_sizes[2] / 2;   // 1600000

    float* ws       = (float*)d_ws;
    float* WT       = ws;                          // 128*128
    float* wc       = WT + D * D;                  // 8*128
    unsigned* gmaxe = (unsigned*)(wc + NH * D);    // 2 (pad 4)
    float* gmaxf    = (float*)(gmaxe + 4);         // 1 (pad 4)
    float* s_src    = gmaxf + 4;                   // N*8
    float* s_trg    = s_src + (size_t)N * NH;      // N*8
    int*   counts   = (int*)(s_trg + (size_t)N * NH);  // N
    int*   cursor   = counts + N;                  // N
    int*   bsum     = cursor + N;                  // 128
    int*   perm_src = bsum + 128;                  // E
    unsigned short* projb = (unsigned short*)(perm_src + E);  // N*128 bf16

    const int NB = (N + SCAN_BS - 1) / SCAN_BS;    // 98
    const int PB = (N + TNODES - 1) / TNODES;      // 1563

    hipMemsetAsync(counts, 0, (size_t)N * sizeof(int), stream);
    hipMemsetAsync(gmaxe, 0, 4 * sizeof(unsigned), stream);

    prep_kernel<<<(D * D + NH * D + 255) / 256, 256, 0, stream>>>(W_src, W_trg, a_trg, WT, wc);
    projhist_kernel<<<PB + HIST_BLOCKS, 256, 0, stream>>>(
        src, trg, WT, a_src, wc, ei, projb, s_src, s_trg, gmaxe, counts, N, E, PB);
    scan1_kernel<<<NB, SCAN_BS, 0, stream>>>(counts, cursor, bsum, N);
    scan2_kernel<<<1, 128, 0, stream>>>(bsum, NB, gmaxe, gmaxf);
    scan3_kernel<<<NB, SCAN_BS, 0, stream>>>(cursor, bsum, N);
    scatter_kernel<<<(E / 2 + 255) / 256, 256, 0, stream>>>(ei, cursor, perm_src, E);
    agg_kernel<<<N, 64, 0, stream>>>(cursor, counts, perm_src,
                                     s_src, s_trg, projb, gmaxf, out);
}